// Round 3
// baseline (241.796 us; speedup 1.0000x reference)
//
#include <hip/hip_runtime.h>
#include <hip/hip_bf16.h>

using bf16 = __hip_bfloat16;
typedef __attribute__((ext_vector_type(8))) short short8;   // 8 bf16 = 4 VGPRs (MFMA a/b frag)
typedef __attribute__((ext_vector_type(4))) float floatx4;  // MFMA c/d frag

#define NEG_INF (-__builtin_huge_valf())

// async global->LDS, 16B per lane. LDS dest is wave-uniform base + lane*16.
__device__ __forceinline__ void gld_lds16(const void* g, void* l) {
  __builtin_amdgcn_global_load_lds(
      (const __attribute__((address_space(1))) unsigned int*)g,
      (__attribute__((address_space(3))) unsigned int*)l, 16, 0, 0);
}

__device__ __forceinline__ void cvt8(const float4& a, const float4& b, bf16* t) {
  t[0] = __float2bfloat16(a.x); t[1] = __float2bfloat16(a.y);
  t[2] = __float2bfloat16(a.z); t[3] = __float2bfloat16(a.w);
  t[4] = __float2bfloat16(b.x); t[5] = __float2bfloat16(b.y);
  t[6] = __float2bfloat16(b.z); t[7] = __float2bfloat16(b.w);
}

// ---------------- weight fp32 -> bf16 (qw ++ kw, 524288 elements) ----------
__global__ void cvt_w(const float* __restrict__ qw, const float* __restrict__ kw,
                      bf16* __restrict__ qwo, bf16* __restrict__ kwo) {
  const int i = blockIdx.x * blockDim.x + threadIdx.x;   // 65536 threads, 8 elems each
  const long e = (long)i << 3;
  const float* src = (e < 262144) ? qw + e : kw + (e - 262144);
  bf16*        dst = (e < 262144) ? qwo + e : kwo + (e - 262144);
  float4 a = *(const float4*)src;
  float4 b = *(const float4*)(src + 4);
  bf16 t[8];
  cvt8(a, b, t);
  *(short8*)dst = *(short8*)t;
}

// ---------------- fused projection: out_bf16 = cvt(A_f32)·W_bf16^T + b -----
// blockIdx.x in [0,64) -> Q rows, [64,192) -> K rows; 768 blocks = 3/CU.
// A-side: fp32 load + in-reg cvt + ds_write. B-side: async DMA (bf16 weights).
// K-unrolled 2x per barrier (two 128x32 sub-tiles) to halve barrier drains.
__global__ __launch_bounds__(256) void proj_fused(const float* __restrict__ X,
                                                  const float* __restrict__ Y,
                                                  const bf16* __restrict__ qw,
                                                  const bf16* __restrict__ kw,
                                                  const float* __restrict__ qb,
                                                  const float* __restrict__ kb,
                                                  bf16* __restrict__ qo,
                                                  bf16* __restrict__ ko) {
  __shared__ bf16 sA[2][128 * 32];
  __shared__ bf16 sB[2][128 * 32];
  const int mt = blockIdx.x;
  const bool isQ = mt < 64;
  const float* A    = isQ ? X  : Y;
  const bf16*  W    = isQ ? qw : kw;
  const float* bias = isQ ? qb : kb;
  bf16* out         = isQ ? qo : ko;
  const int m0 = (isQ ? mt : mt - 64) * 128;
  const int n0 = blockIdx.y * 128;

  const int tid  = threadIdx.x;
  const int lane = tid & 63;
  const int w    = tid >> 6;
  const int wm   = (w >> 1) * 64;
  const int wn   = (w & 1) * 64;
  const int st_row = lane >> 2;
  const int st_col = (lane & 3) * 8;
  const int frag_m = lane & 15;
  const int frag_k = (lane >> 4) * 8;

  floatx4 acc[4][4];
  #pragma unroll
  for (int mi = 0; mi < 4; ++mi)
    #pragma unroll
    for (int ni = 0; ni < 4; ++ni)
      acc[mi][ni] = (floatx4){0.f, 0.f, 0.f, 0.f};

  for (int kt = 0; kt < 512; kt += 64) {
    // B-side: async DMA both sub-tiles (2 issues/wave per sub-tile)
    #pragma unroll
    for (int h = 0; h < 2; ++h)
      #pragma unroll
      for (int j = 0; j < 2; ++j) {
        const int r = (w << 5) + (j << 4);
        const bf16* gb = W + (size_t)(n0 + r + st_row) * 512 + kt + h * 32 + st_col;
        gld_lds16(gb, &sB[h][r * 32]);
      }
    // A-side: fp32 load, cvt, ds_write (both sub-tiles)
    #pragma unroll
    for (int h = 0; h < 2; ++h)
      #pragma unroll
      for (int j = 0; j < 2; ++j) {
        const int row = (w << 5) + (j << 4) + st_row;
        const float* ga = A + (size_t)(m0 + row) * 512 + kt + h * 32 + st_col;
        float4 a0 = *(const float4*)ga;
        float4 a1 = *(const float4*)(ga + 4);
        bf16 ta[8];
        cvt8(a0, a1, ta);
        *(short8*)(&sA[h][row * 32 + st_col]) = *(short8*)ta;
      }
    __syncthreads();

    #pragma unroll
    for (int h = 0; h < 2; ++h) {
      short8 af[4], bfv[4];
      const bf16* pa = &sA[h][(wm + frag_m) * 32 + frag_k];
      const bf16* pb = &sB[h][(wn + frag_m) * 32 + frag_k];
      #pragma unroll
      for (int i = 0; i < 4; ++i) af[i]  = *(const short8*)(pa + i * 16 * 32);
      #pragma unroll
      for (int i = 0; i < 4; ++i) bfv[i] = *(const short8*)(pb + i * 16 * 32);
      #pragma unroll
      for (int mi = 0; mi < 4; ++mi)
        #pragma unroll
        for (int ni = 0; ni < 4; ++ni)
          acc[mi][ni] = __builtin_amdgcn_mfma_f32_16x16x32_bf16(af[mi], bfv[ni],
                                                                acc[mi][ni], 0, 0, 0);
    }
    __syncthreads();
  }

  const int col = lane & 15;             // C/D: col = lane&15, row = (lane>>4)*4 + reg
  const int rbase = (lane >> 4) * 4;
  #pragma unroll
  for (int ni = 0; ni < 4; ++ni) {
    const int gn = n0 + wn + ni * 16 + col;
    const float b = bias[gn];
    #pragma unroll
    for (int mi = 0; mi < 4; ++mi) {
      const int gm = m0 + wm + mi * 16 + rbase;
      #pragma unroll
      for (int r = 0; r < 4; ++r)
        out[(size_t)(gm + r) * 512 + gn] = __float2bfloat16(acc[mi][ni][r] + b);
    }
  }
}

// ---------------- QK^T: out_f32 = (Q·K^T)/64, mask -> -inf -----------------
// m97 structure + 2x K-unroll per barrier. 2048 blocks.
__global__ __launch_bounds__(256) void qk_gemm(const bf16* __restrict__ Q,
                                               const bf16* __restrict__ Kp,
                                               const unsigned char* __restrict__ mask,
                                               float* __restrict__ out) {
  __shared__ bf16 sA[2][128 * 32];
  __shared__ bf16 sB[2][128 * 32];
  const int b = blockIdx.z;
  const bf16* A  = Q  + (size_t)b * 2048 * 512;
  const bf16* Bm = Kp + (size_t)b * 4096 * 512;
  float* ob = out + (size_t)b * 2048 * 4096;
  const unsigned char* mb = mask + (size_t)b * 4096;
  const int m0 = blockIdx.x * 128;
  const int n0 = blockIdx.y * 128;

  const int tid  = threadIdx.x;
  const int lane = tid & 63;
  const int w    = tid >> 6;
  const int wm   = (w >> 1) * 64;
  const int wn   = (w & 1) * 64;
  const int st_row = lane >> 2;
  const int st_col = (lane & 3) * 8;
  const int frag_m = lane & 15;
  const int frag_k = (lane >> 4) * 8;

  floatx4 acc[4][4];
  #pragma unroll
  for (int mi = 0; mi < 4; ++mi)
    #pragma unroll
    for (int ni = 0; ni < 4; ++ni)
      acc[mi][ni] = (floatx4){0.f, 0.f, 0.f, 0.f};

  for (int kt = 0; kt < 512; kt += 64) {
    #pragma unroll
    for (int h = 0; h < 2; ++h)
      #pragma unroll
      for (int j = 0; j < 2; ++j) {
        const int r = (w << 5) + (j << 4);
        const bf16* ga = A  + (size_t)(m0 + r + st_row) * 512 + kt + h * 32 + st_col;
        const bf16* gb = Bm + (size_t)(n0 + r + st_row) * 512 + kt + h * 32 + st_col;
        gld_lds16(ga, &sA[h][r * 32]);
        gld_lds16(gb, &sB[h][r * 32]);
      }
    __syncthreads();

    #pragma unroll
    for (int h = 0; h < 2; ++h) {
      short8 af[4], bfv[4];
      const bf16* pa = &sA[h][(wm + frag_m) * 32 + frag_k];
      const bf16* pb = &sB[h][(wn + frag_m) * 32 + frag_k];
      #pragma unroll
      for (int i = 0; i < 4; ++i) af[i]  = *(const short8*)(pa + i * 16 * 32);
      #pragma unroll
      for (int i = 0; i < 4; ++i) bfv[i] = *(const short8*)(pb + i * 16 * 32);
      #pragma unroll
      for (int mi = 0; mi < 4; ++mi)
        #pragma unroll
        for (int ni = 0; ni < 4; ++ni)
          acc[mi][ni] = __builtin_amdgcn_mfma_f32_16x16x32_bf16(af[mi], bfv[ni],
                                                                acc[mi][ni], 0, 0, 0);
    }
    __syncthreads();
  }

  const int col = lane & 15;
  const int rbase = (lane >> 4) * 4;
  const float scale = 1.0f / 64.0f;      // 1 / (N_HEADS * sqrt(HEAD_DIM))
  #pragma unroll
  for (int ni = 0; ni < 4; ++ni) {
    const int gn = n0 + wn + ni * 16 + col;
    const bool msk = mb[gn] != 0;
    #pragma unroll
    for (int mi = 0; mi < 4; ++mi) {
      const int gm = m0 + wm + mi * 16 + rbase;
      #pragma unroll
      for (int r = 0; r < 4; ++r)
        ob[(size_t)(gm + r) * 4096 + gn] = msk ? NEG_INF : acc[mi][ni][r] * scale;
    }
  }
}

extern "C" void kernel_launch(void* const* d_in, const int* in_sizes, int n_in,
                              void* d_out, int out_size, void* d_ws, size_t ws_size,
                              hipStream_t stream) {
  const float* query = (const float*)d_in[0];
  const float* keys  = (const float*)d_in[1];
  const unsigned char* mask = (const unsigned char*)d_in[2];  // numpy bool = 1B
  const float* q_w = (const float*)d_in[3];
  const float* q_b = (const float*)d_in[4];
  const float* k_w = (const float*)d_in[5];
  const float* k_b = (const float*)d_in[6];
  float* out = (float*)d_out;

  const int B = 4, T = 2048, S = 4096, D = 512;
  const int nq = B * T * D;   // 4194304
  const int nk = B * S * D;   // 8388608
  const int nw = D * D;       // 262144

  // workspace carve (bf16): Q_proj (8 MiB), K_proj (16 MiB), qw, kw (0.5 MiB ea)
  char* ws = (char*)d_ws;
  bf16* q_proj = (bf16*)(ws);
  bf16* k_proj = (bf16*)(ws + (size_t)nq * 2);
  bf16* qw_bf  = (bf16*)(ws + (size_t)(nq + nk) * 2);
  bf16* kw_bf  = (bf16*)(ws + (size_t)(nq + nk + nw) * 2);

  cvt_w<<<256, 256, 0, stream>>>(q_w, k_w, qw_bf, kw_bf);
  proj_fused<<<dim3(192, D / 128), 256, 0, stream>>>(query, keys, qw_bf, kw_bf,
                                                     q_b, k_b, q_proj, k_proj);
  qk_gemm<<<dim3(T / 128, S / 128, B), 256, 0, stream>>>(q_proj, k_proj, mask, out);
}

// Round 4
// 231.642 us; speedup vs baseline: 1.0438x; 1.0438x over previous
//
#include <hip/hip_runtime.h>
#include <hip/hip_bf16.h>

using bf16 = __hip_bfloat16;
typedef __attribute__((ext_vector_type(8))) short short8;     // 8 bf16 (4 VGPRs) MFMA a/b frag
typedef __attribute__((ext_vector_type(16))) float floatx16;  // 32x32 MFMA c/d frag

#define NEG_INF (-__builtin_huge_valf())

// async global->LDS, 16B per lane. LDS dest is wave-uniform base + lane*16.
__device__ __forceinline__ void gld_lds16(const void* g, void* l) {
  __builtin_amdgcn_global_load_lds(
      (const __attribute__((address_space(1))) unsigned int*)g,
      (__attribute__((address_space(3))) unsigned int*)l, 16, 0, 0);
}

__device__ __forceinline__ void cvt8(const float4& a, const float4& b, bf16* t) {
  t[0] = __float2bfloat16(a.x); t[1] = __float2bfloat16(a.y);
  t[2] = __float2bfloat16(a.z); t[3] = __float2bfloat16(a.w);
  t[4] = __float2bfloat16(b.x); t[5] = __float2bfloat16(b.y);
  t[6] = __float2bfloat16(b.z); t[7] = __float2bfloat16(b.w);
}

// ---------------- weight fp32 -> bf16 (qw ++ kw, 524288 elements) ----------
__global__ void cvt_w(const float* __restrict__ qw, const float* __restrict__ kw,
                      bf16* __restrict__ qwo, bf16* __restrict__ kwo) {
  const int i = blockIdx.x * blockDim.x + threadIdx.x;   // 65536 threads, 8 elems each
  const long e = (long)i << 3;
  const float* src = (e < 262144) ? qw + e : kw + (e - 262144);
  bf16*        dst = (e < 262144) ? qwo + e : kwo + (e - 262144);
  float4 a = *(const float4*)src;
  float4 b = *(const float4*)(src + 4);
  bf16 t[8];
  cvt8(a, b, t);
  *(short8*)dst = *(short8*)t;
}

// 32x32x16 MFMA block: wave covers 64x64 as 2x2 of 32x32 tiles.
// A/B operand: m|n = lane&31, k = (lane>>5)*8 + j  (row-major [rows][32] LDS tile)
// C/D: col = lane&31, row = (reg&3) + 8*(reg>>2) + 4*(lane>>5)   [m74/m101]
__device__ __forceinline__ void mfma_tile32(const bf16* sAh, const bf16* sBh,
                                            int wm, int wn, int lane,
                                            floatx16 acc[2][2]) {
  const int fm = lane & 31;
  const int fk = (lane >> 5) * 8;
  #pragma unroll
  for (int ks = 0; ks < 2; ++ks) {        // two K=16 steps per 32-wide tile
    short8 a0 = *(const short8*)(sAh + (wm +  0 + fm) * 32 + ks * 16 + fk);
    short8 a1 = *(const short8*)(sAh + (wm + 32 + fm) * 32 + ks * 16 + fk);
    short8 b0 = *(const short8*)(sBh + (wn +  0 + fm) * 32 + ks * 16 + fk);
    short8 b1 = *(const short8*)(sBh + (wn + 32 + fm) * 32 + ks * 16 + fk);
    acc[0][0] = __builtin_amdgcn_mfma_f32_32x32x16_bf16(a0, b0, acc[0][0], 0, 0, 0);
    acc[0][1] = __builtin_amdgcn_mfma_f32_32x32x16_bf16(a0, b1, acc[0][1], 0, 0, 0);
    acc[1][0] = __builtin_amdgcn_mfma_f32_32x32x16_bf16(a1, b0, acc[1][0], 0, 0, 0);
    acc[1][1] = __builtin_amdgcn_mfma_f32_32x32x16_bf16(a1, b1, acc[1][1], 0, 0, 0);
  }
}

// ---------------- fused projection: out_bf16 = cvt(A_f32)·W_bf16^T + b -----
// blockIdx.x in [0,64) -> Q rows, [64,192) -> K rows; 768 blocks = 3/CU.
__global__ __launch_bounds__(256) void proj_fused(const float* __restrict__ X,
                                                  const float* __restrict__ Y,
                                                  const bf16* __restrict__ qw,
                                                  const bf16* __restrict__ kw,
                                                  const float* __restrict__ qb,
                                                  const float* __restrict__ kb,
                                                  bf16* __restrict__ qo,
                                                  bf16* __restrict__ ko) {
  __shared__ bf16 sA[2][128 * 32];
  __shared__ bf16 sB[2][128 * 32];
  const int mt = blockIdx.x;
  const bool isQ = mt < 64;
  const float* A    = isQ ? X  : Y;
  const bf16*  W    = isQ ? qw : kw;
  const float* bias = isQ ? qb : kb;
  bf16* out         = isQ ? qo : ko;
  const int m0 = (isQ ? mt : mt - 64) * 128;
  const int n0 = blockIdx.y * 128;

  const int tid  = threadIdx.x;
  const int lane = tid & 63;
  const int w    = tid >> 6;
  const int wm   = (w >> 1) * 64;
  const int wn   = (w & 1) * 64;
  const int st_row = lane >> 2;
  const int st_col = (lane & 3) * 8;

  floatx16 acc[2][2];
  #pragma unroll
  for (int mi = 0; mi < 2; ++mi)
    #pragma unroll
    for (int ni = 0; ni < 2; ++ni)
      #pragma unroll
      for (int r = 0; r < 16; ++r)
        acc[mi][ni][r] = 0.f;

  for (int kt = 0; kt < 512; kt += 64) {
    // B-side: async DMA both 128x32 sub-tiles
    #pragma unroll
    for (int h = 0; h < 2; ++h)
      #pragma unroll
      for (int j = 0; j < 2; ++j) {
        const int r = (w << 5) + (j << 4);
        const bf16* gb = W + (size_t)(n0 + r + st_row) * 512 + kt + h * 32 + st_col;
        gld_lds16(gb, &sB[h][r * 32]);
      }
    // A-side: fp32 load, cvt, ds_write
    #pragma unroll
    for (int h = 0; h < 2; ++h)
      #pragma unroll
      for (int j = 0; j < 2; ++j) {
        const int row = (w << 5) + (j << 4) + st_row;
        const float* ga = A + (size_t)(m0 + row) * 512 + kt + h * 32 + st_col;
        float4 a0 = *(const float4*)ga;
        float4 a1 = *(const float4*)(ga + 4);
        bf16 ta[8];
        cvt8(a0, a1, ta);
        *(short8*)(&sA[h][row * 32 + st_col]) = *(short8*)ta;
      }
    __syncthreads();

    #pragma unroll
    for (int h = 0; h < 2; ++h)
      mfma_tile32(sA[h], sB[h], wm, wn, lane, acc);
    __syncthreads();
  }

  const int col = lane & 31;
  const int rhi = (lane >> 5) * 4;
  #pragma unroll
  for (int ni = 0; ni < 2; ++ni) {
    const int gn = n0 + wn + ni * 32 + col;
    const float b = bias[gn];
    #pragma unroll
    for (int mi = 0; mi < 2; ++mi) {
      #pragma unroll
      for (int reg = 0; reg < 16; ++reg) {
        const int row = (reg & 3) + 8 * (reg >> 2) + rhi;
        out[(size_t)(m0 + wm + mi * 32 + row) * 512 + gn] =
            __float2bfloat16(acc[mi][ni][reg] + b);
      }
    }
  }
}

// ---------------- QK^T: out_f32 = (Q·K^T)/64, mask -> -inf -----------------
__global__ __launch_bounds__(256) void qk_gemm(const bf16* __restrict__ Q,
                                               const bf16* __restrict__ Kp,
                                               const unsigned char* __restrict__ mask,
                                               float* __restrict__ out) {
  __shared__ bf16 sA[2][128 * 32];
  __shared__ bf16 sB[2][128 * 32];
  const int b = blockIdx.z;
  const bf16* A  = Q  + (size_t)b * 2048 * 512;
  const bf16* Bm = Kp + (size_t)b * 4096 * 512;
  float* ob = out + (size_t)b * 2048 * 4096;
  const unsigned char* mb = mask + (size_t)b * 4096;
  const int m0 = blockIdx.x * 128;
  const int n0 = blockIdx.y * 128;

  const int tid  = threadIdx.x;
  const int lane = tid & 63;
  const int w    = tid >> 6;
  const int wm   = (w >> 1) * 64;
  const int wn   = (w & 1) * 64;
  const int st_row = lane >> 2;
  const int st_col = (lane & 3) * 8;

  floatx16 acc[2][2];
  #pragma unroll
  for (int mi = 0; mi < 2; ++mi)
    #pragma unroll
    for (int ni = 0; ni < 2; ++ni)
      #pragma unroll
      for (int r = 0; r < 16; ++r)
        acc[mi][ni][r] = 0.f;

  for (int kt = 0; kt < 512; kt += 64) {
    #pragma unroll
    for (int h = 0; h < 2; ++h)
      #pragma unroll
      for (int j = 0; j < 2; ++j) {
        const int r = (w << 5) + (j << 4);
        const bf16* ga = A  + (size_t)(m0 + r + st_row) * 512 + kt + h * 32 + st_col;
        const bf16* gb = Bm + (size_t)(n0 + r + st_row) * 512 + kt + h * 32 + st_col;
        gld_lds16(ga, &sA[h][r * 32]);
        gld_lds16(gb, &sB[h][r * 32]);
      }
    __syncthreads();

    #pragma unroll
    for (int h = 0; h < 2; ++h)
      mfma_tile32(sA[h], sB[h], wm, wn, lane, acc);
    __syncthreads();
  }

  const int col = lane & 31;
  const int rhi = (lane >> 5) * 4;
  const float scale = 1.0f / 64.0f;      // 1 / (N_HEADS * sqrt(HEAD_DIM))
  #pragma unroll
  for (int ni = 0; ni < 2; ++ni) {
    const int gn = n0 + wn + ni * 32 + col;
    const bool msk = mb[gn] != 0;
    #pragma unroll
    for (int mi = 0; mi < 2; ++mi) {
      #pragma unroll
      for (int reg = 0; reg < 16; ++reg) {
        const int row = (reg & 3) + 8 * (reg >> 2) + rhi;
        ob[(size_t)(m0 + wm + mi * 32 + row) * 4096 + gn] =
            msk ? NEG_INF : acc[mi][ni][reg] * scale;
      }
    }
  }
}

extern "C" void kernel_launch(void* const* d_in, const int* in_sizes, int n_in,
                              void* d_out, int out_size, void* d_ws, size_t ws_size,
                              hipStream_t stream) {
  const float* query = (const float*)d_in[0];
  const float* keys  = (const float*)d_in[1];
  const unsigned char* mask = (const unsigned char*)d_in[2];  // numpy bool = 1B
  const float* q_w = (const float*)d_in[3];
  const float* q_b = (const float*)d_in[4];
  const float* k_w = (const float*)d_in[5];
  const float* k_b = (const float*)d_in[6];
  float* out = (float*)d_out;

  const int B = 4, T = 2048, S = 4096, D = 512;
  const int nq = B * T * D;   // 4194304
  const int nk = B * S * D;   // 8388608
  const int nw = D * D;       // 262144

  // workspace carve (bf16): Q_proj (8 MiB), K_proj (16 MiB), qw, kw (0.5 MiB ea)
  char* ws = (char*)d_ws;
  bf16* q_proj = (bf16*)(ws);
  bf16* k_proj = (bf16*)(ws + (size_t)nq * 2);
  bf16* qw_bf  = (bf16*)(ws + (size_t)(nq + nk) * 2);
  bf16* kw_bf  = (bf16*)(ws + (size_t)(nq + nk + nw) * 2);

  cvt_w<<<256, 256, 0, stream>>>(q_w, k_w, qw_bf, kw_bf);
  proj_fused<<<dim3(192, D / 128), 256, 0, stream>>>(query, keys, qw_bf, kw_bf,
                                                     q_b, k_b, q_proj, k_proj);
  qk_gemm<<<dim3(T / 128, S / 128, B), 256, 0, stream>>>(q_proj, k_proj, mask, out);
}